// Round 2
// baseline (292.121 us; speedup 1.0000x reference)
//
#include <hip/hip_runtime.h>

#define L_LEN   262144
#define OUT_LEN 262142
#define BATCH   32

typedef float v2f __attribute__((ext_vector_type(2)));

struct KPtrs { const float* p[12]; };

// ---------------- Kernel 1a: pooled[256] = mean over 1024-elem bins of x[0] ----------------
__global__ void pool_kernel(const float* __restrict__ x, float* __restrict__ pooled) {
    int bin = blockIdx.x;          // 256 blocks
    int tid = threadIdx.x;         // 256 threads
    const float4* x4 = (const float4*)(x + bin * 1024);
    float4 v = x4[tid];
    float sum = v.x + v.y + v.z + v.w;
    #pragma unroll
    for (int off = 32; off; off >>= 1) sum += __shfl_down(sum, off);
    __shared__ float wred[4];
    int wave = tid >> 6;
    if ((tid & 63) == 0) wred[wave] = sum;
    __syncthreads();
    if (tid == 0)
        pooled[bin] = (wred[0] + wred[1] + wred[2] + wred[3]) * (1.0f / 1024.0f);
}

// ---------------- Kernel 1b: attention MLP -> softmax s[12] -> raw effective kernels ----------------
// Kraw layout: [5 classes][4 ch][11 taps]; class q includes kernels with k <= 2q+3.
__global__ void attn_kernel(const float* __restrict__ w1, const float* __restrict__ b1,
                            const float* __restrict__ w2, const float* __restrict__ b2,
                            KPtrs kp, const float* __restrict__ pooled_g,
                            float* __restrict__ Kraw) {
    __shared__ float pooled[256];
    __shared__ float h[128];
    __shared__ float logits[12];
    __shared__ float s[12];
    int tid = threadIdx.x;
    pooled[tid] = pooled_g[tid];
    __syncthreads();
    if (tid < 128) {
        float a = b1[tid];
        const float* wr = w1 + tid * 256;
        #pragma unroll 4
        for (int d = 0; d < 256; ++d) a = fmaf(pooled[d], wr[d], a);
        h[tid] = fmaxf(a, 0.0f);
    }
    __syncthreads();
    if (tid < 12) {
        float a = b2[tid];
        const float* wr = w2 + tid * 128;
        #pragma unroll 4
        for (int j = 0; j < 128; ++j) a = fmaf(h[j], wr[j], a);
        logits[tid] = a;
    }
    __syncthreads();
    if (tid == 0) {
        float m = logits[0];
        #pragma unroll
        for (int i = 1; i < 12; ++i) m = fmaxf(m, logits[i]);
        float e[12]; float sum = 0.0f;
        #pragma unroll
        for (int i = 0; i < 12; ++i) { e[i] = expf(logits[i] - m); sum += e[i]; }
        float inv = 1.0f / sum;
        #pragma unroll
        for (int i = 0; i < 12; ++i) s[i] = e[i] * inv;
    }
    __syncthreads();
    constexpr int KSa[12] = {3,3,3,5,5,7,7,7,9,9,11,11};
    if (tid < 220) {
        int q = tid / 44, r = tid % 44, c = r / 11, j = r % 11;
        int kmax = 2 * q + 3;
        float v = 0.0f;
        #pragma unroll
        for (int i = 0; i < 12; ++i) {
            int k = KSa[i];
            if (k <= kmax && j < k) v = fmaf(s[i], kp.p[i][c * k + j], v);
        }
        Kraw[tid] = v;
    }
}

// ---------------- Kernel 2: stats pass — conv (recompute) -> per-block partial sum & sumsq ----------------
// grid 1024 x 256; each thread: 2 chunks of 16 outputs. part[block][8] = {sum[4], sumsq[4]}.
__global__ __launch_bounds__(256) void stats_kernel(const float* __restrict__ x,
                                                    const float* __restrict__ Kraw,
                                                    float* __restrict__ part) {
    float Kc[4][11];
    const float* K4 = Kraw + 4 * 44;    // full class (kmax=11)
    #pragma unroll
    for (int c = 0; c < 4; ++c)
        #pragma unroll
        for (int j = 0; j < 11; ++j) Kc[c][j] = K4[c * 11 + j];

    float ssum[4] = {0,0,0,0}, ssq[4] = {0,0,0,0};
    int tid0 = blockIdx.x * 256 + threadIdx.x;
    #pragma unroll
    for (int it = 0; it < 2; ++it) {
        int cid = tid0 + it * 262144;
        int b  = cid >> 14;              // 16384 chunks per batch
        int ch = cid & 16383;
        int t0 = ch << 4;
        const float* xb = x + b * L_LEN;
        if (ch != 16383) {
            float xv[28];
            const float4* xp = (const float4*)(xb + t0);
            #pragma unroll
            for (int i = 0; i < 7; ++i) {
                float4 a = xp[i];
                xv[4*i] = a.x; xv[4*i+1] = a.y; xv[4*i+2] = a.z; xv[4*i+3] = a.w;
            }
            #pragma unroll
            for (int c = 0; c < 4; ++c) {
                #pragma unroll
                for (int p = 0; p < 16; ++p) {
                    float v = 0.0f;
                    #pragma unroll
                    for (int j = 0; j < 11; ++j) v = fmaf(Kc[c][j], xv[p + j], v);
                    ssum[c] += v;
                    ssq[c] = fmaf(v, v, ssq[c]);
                }
            }
        } else {
            // tail chunk: t in [t0, t0+13] valid; per-position cumulative kernel class
            for (int tt = 0; tt < 14; ++tt) {
                int t = t0 + tt;
                int rem = L_LEN - t;                 // 16..3
                int q = (rem - 3) >> 1; if (q > 4) q = 4;
                int kmax = 2 * q + 3;
                const float* Kq = Kraw + q * 44;
                for (int c = 0; c < 4; ++c) {
                    float a = 0.0f;
                    for (int j = 0; j < kmax; ++j) a = fmaf(Kq[c * 11 + j], xb[t + j], a);
                    ssum[c] += a;
                    ssq[c] = fmaf(a, a, ssq[c]);
                }
            }
        }
    }
    // block reduce 8 partials -> part[block][8]
    #pragma unroll
    for (int c = 0; c < 4; ++c) {
        #pragma unroll
        for (int off = 32; off; off >>= 1) {
            ssum[c] += __shfl_down(ssum[c], off);
            ssq[c]  += __shfl_down(ssq[c],  off);
        }
    }
    __shared__ float red[4][8];
    int wave = threadIdx.x >> 6;
    if ((threadIdx.x & 63) == 0) {
        #pragma unroll
        for (int c = 0; c < 4; ++c) { red[wave][c] = ssum[c]; red[wave][4 + c] = ssq[c]; }
    }
    __syncthreads();
    if (threadIdx.x < 8) {
        part[blockIdx.x * 8 + threadIdx.x] =
            red[0][threadIdx.x] + red[1][threadIdx.x] + red[2][threadIdx.x] + red[3][threadIdx.x];
    }
}

// ---------------- Kernel 2b: reduce partials, fold BN into kernel taps + bias ----------------
// 1 block x 512 threads. Wave w reduces value w over 1024 blocks.
__global__ void finalize_kernel(const float* __restrict__ part,
                                const float* __restrict__ gamma, const float* __restrict__ beta,
                                const float* __restrict__ Kraw,
                                float* __restrict__ Kscl, float* __restrict__ biasOut) {
    __shared__ double vals[8];
    __shared__ float g[4];
    int tid = threadIdx.x;
    int w = tid >> 6, lane = tid & 63;
    double s = 0.0;
    #pragma unroll
    for (int i = 0; i < 16; ++i) s += (double)part[(lane + 64 * i) * 8 + w];
    #pragma unroll
    for (int off = 32; off; off >>= 1) s += __shfl_down(s, off);
    if (lane == 0) vals[w] = s;
    __syncthreads();
    if (tid < 4) {
        double N = (double)BATCH * (double)OUT_LEN;
        double mean = vals[tid] / N;
        double var  = vals[4 + tid] / N - mean * mean;
        float gg = gamma[tid] * (float)(1.0 / sqrt(var + 1e-5));
        g[tid] = gg;
        biasOut[tid] = beta[tid] - (float)mean * gg;
    }
    __syncthreads();
    if (tid < 220) {
        int c = (tid / 11) % 4;
        Kscl[tid] = Kraw[tid] * g[c];
    }
}

// ---------------- Kernel 3: write pass — conv with BN-folded taps, ReLU, nt store ----------------
// grid 2048 x 256; one chunk of 16 outputs per thread.
__global__ __launch_bounds__(256) void write_kernel(const float* __restrict__ x,
                                                    const float* __restrict__ Kscl,
                                                    const float* __restrict__ biasv,
                                                    float* __restrict__ out) {
    float Kc[4][11];
    const float* K4 = Kscl + 4 * 44;
    #pragma unroll
    for (int c = 0; c < 4; ++c)
        #pragma unroll
        for (int j = 0; j < 11; ++j) Kc[c][j] = K4[c * 11 + j];
    float bias[4] = {biasv[0], biasv[1], biasv[2], biasv[3]};

    int cid = blockIdx.x * 256 + threadIdx.x;
    int b  = cid >> 14;
    int ch = cid & 16383;
    int t0 = ch << 4;
    const float* xb = x + b * L_LEN;
    float* ob = out + (b * 4) * OUT_LEN + t0;

    if (ch != 16383) {
        float xv[28];
        const float4* xp = (const float4*)(xb + t0);
        #pragma unroll
        for (int i = 0; i < 7; ++i) {
            float4 a = xp[i];
            xv[4*i] = a.x; xv[4*i+1] = a.y; xv[4*i+2] = a.z; xv[4*i+3] = a.w;
        }
        #pragma unroll
        for (int c = 0; c < 4; ++c) {
            float v[16];
            #pragma unroll
            for (int p = 0; p < 16; ++p) {
                float a = bias[c];
                #pragma unroll
                for (int j = 0; j < 11; ++j) a = fmaf(Kc[c][j], xv[p + j], a);
                v[p] = fmaxf(a, 0.0f);
            }
            v2f* o2 = (v2f*)(ob + c * OUT_LEN);   // 8B-aligned (OUT_LEN even, t0 even)
            #pragma unroll
            for (int p = 0; p < 8; ++p) {
                v2f t; t.x = v[2*p]; t.y = v[2*p+1];
                __builtin_nontemporal_store(t, o2 + p);
            }
        }
    } else {
        // tail chunk: t in [t0, t0+13] valid; per-position cumulative kernel class
        for (int tt = 0; tt < 14; ++tt) {
            int t = t0 + tt;
            int rem = L_LEN - t;
            int q = (rem - 3) >> 1; if (q > 4) q = 4;
            int kmax = 2 * q + 3;
            const float* Kq = Kscl + q * 44;
            for (int c = 0; c < 4; ++c) {
                float a = bias[c];
                for (int j = 0; j < kmax; ++j) a = fmaf(Kq[c * 11 + j], xb[t + j], a);
                out[(b * 4 + c) * OUT_LEN + t] = fmaxf(a, 0.0f);
            }
        }
    }
}

extern "C" void kernel_launch(void* const* d_in, const int* in_sizes, int n_in,
                              void* d_out, int out_size, void* d_ws, size_t ws_size,
                              hipStream_t stream) {
    const float* x     = (const float*)d_in[0];
    const float* w1    = (const float*)d_in[1];
    const float* b1    = (const float*)d_in[2];
    const float* w2    = (const float*)d_in[3];
    const float* b2    = (const float*)d_in[4];
    const float* gamma = (const float*)d_in[5];
    const float* beta  = (const float*)d_in[6];
    KPtrs kp;
    for (int i = 0; i < 12; ++i) kp.p[i] = (const float*)d_in[7 + i];
    float* out = (float*)d_out;

    char* ws = (char*)d_ws;
    float* pooled = (float*)(ws + 0);       // 256 floats
    float* Kraw   = (float*)(ws + 1024);    // 220 floats
    float* Kscl   = (float*)(ws + 2048);    // 220 floats
    float* biasv  = (float*)(ws + 3072);    // 4 floats
    float* part   = (float*)(ws + 4096);    // 1024*8 floats = 32 KB

    pool_kernel<<<dim3(256), dim3(256), 0, stream>>>(x, pooled);
    attn_kernel<<<dim3(1), dim3(256), 0, stream>>>(w1, b1, w2, b2, kp, pooled, Kraw);
    stats_kernel<<<dim3(1024), dim3(256), 0, stream>>>(x, Kraw, part);
    finalize_kernel<<<dim3(1), dim3(512), 0, stream>>>(part, gamma, beta, Kraw, Kscl, biasv);
    write_kernel<<<dim3(2048), dim3(256), 0, stream>>>(x, Kscl, biasv, out);
}

// Round 3
// 130.822 us; speedup vs baseline: 2.2330x; 2.2330x over previous
//
#include <hip/hip_runtime.h>

#define L_LEN   262144
#define OUT_LEN 262142
#define BATCH   32

typedef float v2f __attribute__((ext_vector_type(2)));

struct KPtrs { const float* p[12]; };

// ---------------- Kernel 1a: pooled[256] = mean over 1024-elem bins of x[0] ----------------
__global__ void pool_kernel(const float* __restrict__ x, float* __restrict__ pooled) {
    int bin = blockIdx.x;          // 256 blocks
    int tid = threadIdx.x;         // 256 threads
    const float4* x4 = (const float4*)(x + bin * 1024);
    float4 v = x4[tid];
    float sum = v.x + v.y + v.z + v.w;
    #pragma unroll
    for (int off = 32; off; off >>= 1) sum += __shfl_down(sum, off);
    __shared__ float wred[4];
    int wave = tid >> 6;
    if ((tid & 63) == 0) wred[wave] = sum;
    __syncthreads();
    if (tid == 0)
        pooled[bin] = (wred[0] + wred[1] + wred[2] + wred[3]) * (1.0f / 1024.0f);
}

// ---------------- Kernel 1b: attention MLP -> softmax s[12] -> raw effective kernels ----------------
// Wave-per-row dots: lane loads w1[t][lane*4..+3] (coalesced float4), shuffle-reduce.
// Kraw layout: [5 classes][4 ch][11 taps]; class q includes kernels with k <= 2q+3.
__global__ void attn_kernel(const float* __restrict__ w1, const float* __restrict__ b1,
                            const float* __restrict__ w2, const float* __restrict__ b2,
                            KPtrs kp, const float* __restrict__ pooled_g,
                            float* __restrict__ Kraw) {
    __shared__ float h[128];
    __shared__ float logits[12];
    __shared__ float s[12];
    int tid = threadIdx.x;
    int w = tid >> 6, lane = tid & 63;

    float4 pv = ((const float4*)pooled_g)[lane];   // pooled[4*lane .. +3]
    // layer 1: wave w handles rows t = 32w .. 32w+31
    for (int i = 0; i < 32; ++i) {
        int t = w * 32 + i;
        float4 wv = ((const float4*)(w1 + t * 256))[lane];
        float p = wv.x * pv.x + wv.y * pv.y + wv.z * pv.z + wv.w * pv.w;
        #pragma unroll
        for (int off = 32; off; off >>= 1) p += __shfl_down(p, off);
        if (lane == 0) h[t] = fmaxf(p + b1[t], 0.0f);
    }
    __syncthreads();
    // layer 2: wave w handles rows f = w, w+4, w+8
    for (int f = w; f < 12; f += 4) {
        float2 wv = ((const float2*)(w2 + f * 128))[lane];
        float p = wv.x * h[2 * lane] + wv.y * h[2 * lane + 1];
        #pragma unroll
        for (int off = 32; off; off >>= 1) p += __shfl_down(p, off);
        if (lane == 0) logits[f] = p + b2[f];
    }
    __syncthreads();
    if (tid == 0) {
        float m = logits[0];
        #pragma unroll
        for (int i = 1; i < 12; ++i) m = fmaxf(m, logits[i]);
        float e[12]; float sum = 0.0f;
        #pragma unroll
        for (int i = 0; i < 12; ++i) { e[i] = expf(logits[i] - m); sum += e[i]; }
        float inv = 1.0f / sum;
        #pragma unroll
        for (int i = 0; i < 12; ++i) s[i] = e[i] * inv;
    }
    __syncthreads();
    constexpr int KSa[12] = {3,3,3,5,5,7,7,7,9,9,11,11};
    if (tid < 220) {
        int q = tid / 44, r = tid % 44, c = r / 11, j = r % 11;
        int kmax = 2 * q + 3;
        float v = 0.0f;
        #pragma unroll
        for (int i = 0; i < 12; ++i) {
            int k = KSa[i];
            if (k <= kmax && j < k) v = fmaf(s[i], kp.p[i][c * k + j], v);
        }
        Kraw[tid] = v;
    }
}

// ---------------- Kernel 2: stats pass — conv (recompute) -> per-block partial sum & sumsq ----------------
// grid 2048 x 256; each thread: one chunk of 16 outputs x 4 channels. part[block][8] = {sum[4], sumsq[4]}.
__global__ __launch_bounds__(256, 4) void stats_kernel(const float* __restrict__ x,
                                                       const float* __restrict__ Kraw,
                                                       float* __restrict__ part) {
    float Kc[4][11];
    const float* K4 = Kraw + 4 * 44;    // full class (kmax=11)
    #pragma unroll
    for (int c = 0; c < 4; ++c)
        #pragma unroll
        for (int j = 0; j < 11; ++j) Kc[c][j] = K4[c * 11 + j];

    float ssum[4] = {0,0,0,0}, ssq[4] = {0,0,0,0};
    int cid = blockIdx.x * 256 + threadIdx.x;
    int b  = cid >> 14;              // 16384 chunks per batch row
    int ch = cid & 16383;
    int t0 = ch << 4;
    const float* xb = x + b * L_LEN;
    if (ch != 16383) {
        float xv[28];
        const float4* xp = (const float4*)(xb + t0);
        #pragma unroll
        for (int i = 0; i < 7; ++i) {
            float4 a = xp[i];
            xv[4*i] = a.x; xv[4*i+1] = a.y; xv[4*i+2] = a.z; xv[4*i+3] = a.w;
        }
        #pragma unroll
        for (int c = 0; c < 4; ++c) {
            #pragma unroll
            for (int p = 0; p < 16; ++p) {
                float v = 0.0f;
                #pragma unroll
                for (int j = 0; j < 11; ++j) v = fmaf(Kc[c][j], xv[p + j], v);
                ssum[c] += v;
                ssq[c] = fmaf(v, v, ssq[c]);
            }
        }
    } else {
        // tail chunk: t in [t0, t0+13] valid; per-position cumulative kernel class
        for (int tt = 0; tt < 14; ++tt) {
            int t = t0 + tt;
            int rem = L_LEN - t;                 // 16..3
            int q = (rem - 3) >> 1; if (q > 4) q = 4;
            int kmax = 2 * q + 3;
            const float* Kq = Kraw + q * 44;
            for (int c = 0; c < 4; ++c) {
                float a = 0.0f;
                for (int j = 0; j < kmax; ++j) a = fmaf(Kq[c * 11 + j], xb[t + j], a);
                ssum[c] += a;
                ssq[c] = fmaf(a, a, ssq[c]);
            }
        }
    }
    // block reduce 8 partials -> part[block][8]
    #pragma unroll
    for (int c = 0; c < 4; ++c) {
        #pragma unroll
        for (int off = 32; off; off >>= 1) {
            ssum[c] += __shfl_down(ssum[c], off);
            ssq[c]  += __shfl_down(ssq[c],  off);
        }
    }
    __shared__ float red[4][8];
    int wave = threadIdx.x >> 6;
    if ((threadIdx.x & 63) == 0) {
        #pragma unroll
        for (int c = 0; c < 4; ++c) { red[wave][c] = ssum[c]; red[wave][4 + c] = ssq[c]; }
    }
    __syncthreads();
    if (threadIdx.x < 8) {
        part[blockIdx.x * 8 + threadIdx.x] =
            red[0][threadIdx.x] + red[1][threadIdx.x] + red[2][threadIdx.x] + red[3][threadIdx.x];
    }
}

// ---------------- Kernel 2b: reduce partials, fold BN into kernel taps + bias ----------------
// 1 block x 512 threads. Wave w reduces value w over 2048 blocks.
__global__ void finalize_kernel(const float* __restrict__ part,
                                const float* __restrict__ gamma, const float* __restrict__ beta,
                                const float* __restrict__ Kraw,
                                float* __restrict__ Kscl, float* __restrict__ biasOut) {
    __shared__ double vals[8];
    __shared__ float g[4];
    int tid = threadIdx.x;
    int w = tid >> 6, lane = tid & 63;
    double s = 0.0;
    #pragma unroll
    for (int i = 0; i < 32; ++i) s += (double)part[(lane + 64 * i) * 8 + w];
    #pragma unroll
    for (int off = 32; off; off >>= 1) s += __shfl_down(s, off);
    if (lane == 0) vals[w] = s;
    __syncthreads();
    if (tid < 4) {
        double N = (double)BATCH * (double)OUT_LEN;
        double mean = vals[tid] / N;
        double var  = vals[4 + tid] / N - mean * mean;
        float gg = gamma[tid] * (float)(1.0 / sqrt(var + 1e-5));
        g[tid] = gg;
        biasOut[tid] = beta[tid] - (float)mean * gg;
    }
    __syncthreads();
    if (tid < 220) {
        int c = (tid / 11) % 4;
        Kscl[tid] = Kraw[tid] * g[c];
    }
}

// ---------------- Kernel 3: write pass — channel-split conv, BN-folded, ReLU, cached stores ----------------
// grid 8192 x 256; thread = one chunk of 16 outputs for ONE channel (c block-uniform -> taps in SGPRs).
__global__ __launch_bounds__(256, 4) void write_kernel(const float* __restrict__ x,
                                                       const float* __restrict__ Kscl,
                                                       const float* __restrict__ biasv,
                                                       float* __restrict__ out) {
    int gid = blockIdx.x * 256 + threadIdx.x;
    int c = gid >> 19;               // 524288 chunks per channel; uniform per block
    int r = gid & 524287;
    int b  = r >> 14;
    int ch = r & 16383;
    int t0 = ch << 4;

    float K[11];
    const float* Kc = Kscl + 4 * 44 + c * 11;
    #pragma unroll
    for (int j = 0; j < 11; ++j) K[j] = Kc[j];
    float bias = biasv[c];

    const float* xb = x + b * L_LEN;
    float* ob = out + (b * 4 + c) * OUT_LEN + t0;

    if (ch != 16383) {
        float xv[28];
        const float4* xp = (const float4*)(xb + t0);
        #pragma unroll
        for (int i = 0; i < 7; ++i) {
            float4 a = xp[i];
            xv[4*i] = a.x; xv[4*i+1] = a.y; xv[4*i+2] = a.z; xv[4*i+3] = a.w;
        }
        float v[16];
        #pragma unroll
        for (int p = 0; p < 16; ++p) {
            float a = bias;
            #pragma unroll
            for (int j = 0; j < 11; ++j) a = fmaf(K[j], xv[p + j], a);
            v[p] = fmaxf(a, 0.0f);
        }
        v2f* o2 = (v2f*)ob;   // 8B-aligned (row base even, t0 even)
        #pragma unroll
        for (int p = 0; p < 8; ++p) {
            v2f t; t.x = v[2*p]; t.y = v[2*p+1];
            o2[p] = t;
        }
    } else {
        // tail chunk: t in [t0, t0+13] valid; per-position cumulative kernel class
        for (int tt = 0; tt < 14; ++tt) {
            int t = t0 + tt;
            int rem = L_LEN - t;
            int q = (rem - 3) >> 1; if (q > 4) q = 4;
            int kmax = 2 * q + 3;
            const float* Kq = Kscl + q * 44;
            float a = bias;
            for (int j = 0; j < kmax; ++j) a = fmaf(Kq[c * 11 + j], xb[t + j], a);
            out[(b * 4 + c) * OUT_LEN + t] = fmaxf(a, 0.0f);
        }
    }
}

extern "C" void kernel_launch(void* const* d_in, const int* in_sizes, int n_in,
                              void* d_out, int out_size, void* d_ws, size_t ws_size,
                              hipStream_t stream) {
    const float* x     = (const float*)d_in[0];
    const float* w1    = (const float*)d_in[1];
    const float* b1    = (const float*)d_in[2];
    const float* w2    = (const float*)d_in[3];
    const float* b2    = (const float*)d_in[4];
    const float* gamma = (const float*)d_in[5];
    const float* beta  = (const float*)d_in[6];
    KPtrs kp;
    for (int i = 0; i < 12; ++i) kp.p[i] = (const float*)d_in[7 + i];
    float* out = (float*)d_out;

    char* ws = (char*)d_ws;
    float* pooled = (float*)(ws + 0);       // 256 floats
    float* Kraw   = (float*)(ws + 1024);    // 220 floats
    float* Kscl   = (float*)(ws + 2048);    // 220 floats
    float* biasv  = (float*)(ws + 3072);    // 4 floats
    float* part   = (float*)(ws + 4096);    // 2048*8 floats = 64 KB

    pool_kernel<<<dim3(256), dim3(256), 0, stream>>>(x, pooled);
    attn_kernel<<<dim3(1), dim3(256), 0, stream>>>(w1, b1, w2, b2, kp, pooled, Kraw);
    stats_kernel<<<dim3(2048), dim3(256), 0, stream>>>(x, Kraw, part);
    finalize_kernel<<<dim3(1), dim3(512), 0, stream>>>(part, gamma, beta, Kraw, Kscl, biasv);
    write_kernel<<<dim3(8192), dim3(256), 0, stream>>>(x, Kscl, biasv, out);
}

// Round 4
// 112.127 us; speedup vs baseline: 2.6053x; 1.1667x over previous
//
#include <hip/hip_runtime.h>

#define L_LEN   262144
#define OUT_LEN 262142
#define BATCH   32

typedef float v2f __attribute__((ext_vector_type(2)));
typedef float v4f __attribute__((ext_vector_type(4)));

struct KPtrs { const float* p[12]; };

// ---------------- Kernel 1a: pooled[256] = mean over 1024-elem bins of x[0] ----------------
__global__ void pool_kernel(const float* __restrict__ x, float* __restrict__ pooled) {
    int bin = blockIdx.x;          // 256 blocks
    int tid = threadIdx.x;         // 256 threads
    const float4* x4 = (const float4*)(x + bin * 1024);
    float4 v = x4[tid];
    float sum = v.x + v.y + v.z + v.w;
    #pragma unroll
    for (int off = 32; off; off >>= 1) sum += __shfl_down(sum, off);
    __shared__ float wred[4];
    int wave = tid >> 6;
    if ((tid & 63) == 0) wred[wave] = sum;
    __syncthreads();
    if (tid == 0)
        pooled[bin] = (wred[0] + wred[1] + wred[2] + wred[3]) * (1.0f / 1024.0f);
}

// ---------------- Kernel 1b: attention MLP -> softmax s[12] -> raw effective kernels ----------------
// 8 waves; wave-per-row dots with coalesced float4 loads + shuffle reduce.
// Kraw layout: [5 classes][4 ch][11 taps]; class q includes kernels with k <= 2q+3.
__global__ void attn_kernel(const float* __restrict__ w1, const float* __restrict__ b1,
                            const float* __restrict__ w2, const float* __restrict__ b2,
                            KPtrs kp, const float* __restrict__ pooled_g,
                            float* __restrict__ Kraw) {
    __shared__ float h[128];
    __shared__ float logits[12];
    __shared__ float s[12];
    int tid = threadIdx.x;               // 512 threads
    int w = tid >> 6, lane = tid & 63;

    float4 pv = ((const float4*)pooled_g)[lane];   // pooled[4*lane .. +3]
    // layer 1: wave w handles rows 16w .. 16w+15
    for (int i = 0; i < 16; ++i) {
        int t = w * 16 + i;
        float4 wv = ((const float4*)(w1 + t * 256))[lane];
        float p = wv.x * pv.x + wv.y * pv.y + wv.z * pv.z + wv.w * pv.w;
        #pragma unroll
        for (int off = 32; off; off >>= 1) p += __shfl_down(p, off);
        if (lane == 0) h[t] = fmaxf(p + b1[t], 0.0f);
    }
    __syncthreads();
    // layer 2: waves 0..3 handle rows f = w, w+4, w+8
    if (w < 4) {
        for (int f = w; f < 12; f += 4) {
            float2 wv = ((const float2*)(w2 + f * 128))[lane];
            float p = wv.x * h[2 * lane] + wv.y * h[2 * lane + 1];
            #pragma unroll
            for (int off = 32; off; off >>= 1) p += __shfl_down(p, off);
            if (lane == 0) logits[f] = p + b2[f];
        }
    }
    __syncthreads();
    if (tid == 0) {
        float m = logits[0];
        #pragma unroll
        for (int i = 1; i < 12; ++i) m = fmaxf(m, logits[i]);
        float e[12]; float sum = 0.0f;
        #pragma unroll
        for (int i = 0; i < 12; ++i) { e[i] = expf(logits[i] - m); sum += e[i]; }
        float inv = 1.0f / sum;
        #pragma unroll
        for (int i = 0; i < 12; ++i) s[i] = e[i] * inv;
    }
    __syncthreads();
    constexpr int KSa[12] = {3,3,3,5,5,7,7,7,9,9,11,11};
    if (tid < 220) {
        int q = tid / 44, r = tid % 44, c = r / 11, j = r % 11;
        int kmax = 2 * q + 3;
        float v = 0.0f;
        #pragma unroll
        for (int i = 0; i < 12; ++i) {
            int k = KSa[i];
            if (k <= kmax && j < k) v = fmaf(s[i], kp.p[i][c * k + j], v);
        }
        Kraw[tid] = v;
    }
}

// ---------------- Kernel 2: stats pass — LDS-tiled conv recompute -> per-block partials ----------------
// grid 2048 x 256; block loops over 4 tiles of 1024 outputs; thread = 4 outputs x 4 channels.
// part layout SoA: part[v*2048 + block], v in {sum0..3, sq0..3}.
__global__ __launch_bounds__(256, 4) void stats_kernel(const float* __restrict__ x,
                                                       const float* __restrict__ Kraw,
                                                       float* __restrict__ part) {
    __shared__ float xt[1040];
    int tid = threadIdx.x;
    float Kc[4][11];                      // uniform loads -> scalar regs
    #pragma unroll
    for (int c = 0; c < 4; ++c)
        #pragma unroll
        for (int j = 0; j < 11; ++j) Kc[c][j] = Kraw[4 * 44 + c * 11 + j];

    float ssum[4] = {0,0,0,0}, ssq[4] = {0,0,0,0};

    for (int it = 0; it < 4; ++it) {
        int T = blockIdx.x + 2048 * it;   // tile id 0..8191
        int b = T >> 8, seg = T & 255;
        int tileBase = seg << 10;
        const float* xb = x + b * L_LEN;
        // stage tile: coalesced float4/lane
        *(float4*)&xt[4 * tid] = *(const float4*)(xb + tileBase + 4 * tid);
        if (tid < 3 && seg != 255)
            *(float4*)&xt[1024 + 4 * tid] = *(const float4*)(xb + tileBase + 1024 + 4 * tid);
        __syncthreads();

        bool tail = (seg == 255) && (tid >= 253);
        if (!tail) {
            float xv[14];
            const float4* xr = (const float4*)&xt[4 * tid];
            float4 r0 = xr[0], r1 = xr[1], r2 = xr[2];
            float2 r3 = *(const float2*)&xt[4 * tid + 12];
            xv[0]=r0.x; xv[1]=r0.y; xv[2]=r0.z; xv[3]=r0.w;
            xv[4]=r1.x; xv[5]=r1.y; xv[6]=r1.z; xv[7]=r1.w;
            xv[8]=r2.x; xv[9]=r2.y; xv[10]=r2.z; xv[11]=r2.w;
            xv[12]=r3.x; xv[13]=r3.y;
            #pragma unroll
            for (int c = 0; c < 4; ++c) {
                #pragma unroll
                for (int p = 0; p < 4; ++p) {
                    float v = 0.0f;
                    #pragma unroll
                    for (int j = 0; j < 11; ++j) v = fmaf(Kc[c][j], xv[p + j], v);
                    ssum[c] += v;
                    ssq[c] = fmaf(v, v, ssq[c]);
                }
            }
        } else {
            int lt0 = 4 * tid;                       // local 1012..1020
            for (int tt = 0; tt < 4; ++tt) {
                int t = tileBase + lt0 + tt;
                if (t >= OUT_LEN) break;
                int rem = L_LEN - t;
                int q = (rem - 3) >> 1; if (q > 4) q = 4;
                int kmax = 2 * q + 3;
                const float* Kq = Kraw + q * 44;
                for (int c = 0; c < 4; ++c) {
                    float a = 0.0f;
                    for (int j = 0; j < kmax; ++j) a = fmaf(Kq[c * 11 + j], xt[lt0 + tt + j], a);
                    ssum[c] += a;
                    ssq[c] = fmaf(a, a, ssq[c]);
                }
            }
        }
        __syncthreads();
    }

    // block reduce 8 partials -> part[v][block]
    #pragma unroll
    for (int c = 0; c < 4; ++c) {
        #pragma unroll
        for (int off = 32; off; off >>= 1) {
            ssum[c] += __shfl_down(ssum[c], off);
            ssq[c]  += __shfl_down(ssq[c],  off);
        }
    }
    __shared__ float red[4][8];
    int wave = tid >> 6;
    if ((tid & 63) == 0) {
        #pragma unroll
        for (int c = 0; c < 4; ++c) { red[wave][c] = ssum[c]; red[wave][4 + c] = ssq[c]; }
    }
    __syncthreads();
    if (tid < 8) {
        part[tid * 2048 + blockIdx.x] =
            red[0][tid] + red[1][tid] + red[2][tid] + red[3][tid];
    }
}

// ---------------- Kernel 2b: reduce partials, fold BN into kernel taps + bias ----------------
// 1 block x 512 threads. Wave w reduces value w over 2048 blocks (coalesced).
__global__ void finalize_kernel(const float* __restrict__ part,
                                const float* __restrict__ gamma, const float* __restrict__ beta,
                                const float* __restrict__ Kraw,
                                float* __restrict__ Kscl, float* __restrict__ biasOut) {
    __shared__ double vals[8];
    __shared__ float g[4];
    int tid = threadIdx.x;
    int w = tid >> 6, lane = tid & 63;
    double s = 0.0;
    #pragma unroll
    for (int i = 0; i < 32; ++i) s += (double)part[w * 2048 + i * 64 + lane];
    #pragma unroll
    for (int off = 32; off; off >>= 1) s += __shfl_down(s, off);
    if (lane == 0) vals[w] = s;
    __syncthreads();
    if (tid < 4) {
        double N = (double)BATCH * (double)OUT_LEN;
        double mean = vals[tid] / N;
        double var  = vals[4 + tid] / N - mean * mean;
        float gg = gamma[tid] * (float)(1.0 / sqrt(var + 1e-5));
        g[tid] = gg;
        biasOut[tid] = beta[tid] - (float)mean * gg;
    }
    __syncthreads();
    if (tid < 220) {
        int c = (tid / 11) % 4;
        Kscl[tid] = Kraw[tid] * g[c];
    }
}

// ---------------- Kernel 3: write pass — LDS-tiled conv, BN-folded, ReLU, coalesced stores ----------------
// grid 8192 = 32b x 256seg; block = 1024-output tile; thread = 4 consecutive outputs x 4 channels.
__global__ __launch_bounds__(256, 4) void write_kernel(const float* __restrict__ x,
                                                       const float* __restrict__ Kscl,
                                                       const float* __restrict__ biasv,
                                                       float* __restrict__ out) {
    __shared__ float xt[1040];
    int tid = threadIdx.x;
    int b = blockIdx.x >> 8, seg = blockIdx.x & 255;
    int tileBase = seg << 10;
    const float* xb = x + b * L_LEN;

    *(float4*)&xt[4 * tid] = *(const float4*)(xb + tileBase + 4 * tid);
    if (tid < 3 && seg != 255)
        *(float4*)&xt[1024 + 4 * tid] = *(const float4*)(xb + tileBase + 1024 + 4 * tid);

    float Kc[4][11], bias[4];            // uniform loads -> scalar regs
    #pragma unroll
    for (int c = 0; c < 4; ++c) {
        #pragma unroll
        for (int j = 0; j < 11; ++j) Kc[c][j] = Kscl[4 * 44 + c * 11 + j];
        bias[c] = biasv[c];
    }
    __syncthreads();

    bool tail = (seg == 255) && (tid >= 253);
    if (!tail) {
        float xv[14];
        const float4* xr = (const float4*)&xt[4 * tid];
        float4 r0 = xr[0], r1 = xr[1], r2 = xr[2];
        float2 r3 = *(const float2*)&xt[4 * tid + 12];
        xv[0]=r0.x; xv[1]=r0.y; xv[2]=r0.z; xv[3]=r0.w;
        xv[4]=r1.x; xv[5]=r1.y; xv[6]=r1.z; xv[7]=r1.w;
        xv[8]=r2.x; xv[9]=r2.y; xv[10]=r2.z; xv[11]=r2.w;
        xv[12]=r3.x; xv[13]=r3.y;
        #pragma unroll
        for (int c = 0; c < 4; ++c) {
            float v[4];
            #pragma unroll
            for (int p = 0; p < 4; ++p) {
                float a = bias[c];
                #pragma unroll
                for (int j = 0; j < 11; ++j) a = fmaf(Kc[c][j], xv[p + j], a);
                v[p] = fmaxf(a, 0.0f);
            }
            float* op = out + (size_t)(4 * b + c) * OUT_LEN + tileBase + 4 * tid;
            if ((c & 1) == 0) {
                // row base % 4 == 0 for even c -> 16B-aligned
                *(v4f*)op = (v4f){v[0], v[1], v[2], v[3]};
            } else {
                // row base % 4 == 2 for odd c -> 8B-aligned
                ((v2f*)op)[0] = (v2f){v[0], v[1]};
                ((v2f*)op)[1] = (v2f){v[2], v[3]};
            }
        }
    } else {
        int lt0 = 4 * tid;
        for (int tt = 0; tt < 4; ++tt) {
            int t = tileBase + lt0 + tt;
            if (t >= OUT_LEN) break;
            int rem = L_LEN - t;
            int q = (rem - 3) >> 1; if (q > 4) q = 4;
            int kmax = 2 * q + 3;
            const float* Kq = Kscl + q * 44;
            for (int c = 0; c < 4; ++c) {
                float a = biasv[c];
                for (int j = 0; j < kmax; ++j) a = fmaf(Kq[c * 11 + j], xt[lt0 + tt + j], a);
                out[(size_t)(4 * b + c) * OUT_LEN + t] = fmaxf(a, 0.0f);
            }
        }
    }
}

extern "C" void kernel_launch(void* const* d_in, const int* in_sizes, int n_in,
                              void* d_out, int out_size, void* d_ws, size_t ws_size,
                              hipStream_t stream) {
    const float* x     = (const float*)d_in[0];
    const float* w1    = (const float*)d_in[1];
    const float* b1    = (const float*)d_in[2];
    const float* w2    = (const float*)d_in[3];
    const float* b2    = (const float*)d_in[4];
    const float* gamma = (const float*)d_in[5];
    const float* beta  = (const float*)d_in[6];
    KPtrs kp;
    for (int i = 0; i < 12; ++i) kp.p[i] = (const float*)d_in[7 + i];
    float* out = (float*)d_out;

    char* ws = (char*)d_ws;
    float* pooled = (float*)(ws + 0);       // 256 floats
    float* Kraw   = (float*)(ws + 1024);    // 220 floats
    float* Kscl   = (float*)(ws + 2048);    // 220 floats
    float* biasv  = (float*)(ws + 3072);    // 4 floats
    float* part   = (float*)(ws + 4096);    // 8*2048 floats = 64 KB

    pool_kernel<<<dim3(256), dim3(256), 0, stream>>>(x, pooled);
    attn_kernel<<<dim3(1), dim3(512), 0, stream>>>(w1, b1, w2, b2, kp, pooled, Kraw);
    stats_kernel<<<dim3(2048), dim3(256), 0, stream>>>(x, Kraw, part);
    finalize_kernel<<<dim3(1), dim3(512), 0, stream>>>(part, gamma, beta, Kraw, Kscl, biasv);
    write_kernel<<<dim3(8192), dim3(256), 0, stream>>>(x, Kscl, biasv, out);
}

// Round 6
// 91.190 us; speedup vs baseline: 3.2034x; 1.2296x over previous
//
#include <hip/hip_runtime.h>

#define L_LEN   262144
#define OUT_LEN 262142
#define BATCH   32
#define NTOT    (32.0 * 262142.0)

typedef float v4f __attribute__((ext_vector_type(4)));

struct KPtrs { const float* p[12]; };

// ============ K1: fused pool + autocorrelation stats ============
// grid 1024 x 256. Block handles 4 consecutive 2048-tiles (tiles never cross rows:
// 128 tiles/row, 4096 tiles total). Accumulates X = sum(x), R_l = sum(x_u*x_{u+l})
// l=0..10 per block (row-local: staging zero-pads past row end). Blocks 0..31 also
// emit pooled bins (row 0). part layout SoA: part[v*1024 + block], v=0 -> X, v=1+l -> R_l.
__global__ __launch_bounds__(256, 4) void stats_pool_kernel(const float* __restrict__ x,
                                                            float* __restrict__ part,
                                                            float* __restrict__ pooled) {
    __shared__ float xt[2064];
    __shared__ float wsum[4];
    int tid = threadIdx.x;
    float X = 0.0f, R[11];
    #pragma unroll
    for (int l = 0; l < 11; ++l) R[l] = 0.0f;

    for (int it = 0; it < 4; ++it) {
        int T = blockIdx.x * 4 + it;       // 0..4095
        int row = T >> 7, seg = T & 127;   // row 0..31, seg 0..127
        int base = seg << 11;
        const float* xb = x + row * L_LEN;
        *(float4*)&xt[4 * tid]        = *(const float4*)(xb + base + 4 * tid);
        *(float4*)&xt[1024 + 4 * tid] = *(const float4*)(xb + base + 1024 + 4 * tid);
        if (tid < 3) {
            float4 v = {0.f, 0.f, 0.f, 0.f};
            if (seg < 127) v = *(const float4*)(xb + base + 2048 + 4 * tid);
            *(float4*)&xt[2048 + 4 * tid] = v;
        }
        __syncthreads();

        float xv[18];
        const float4* xr = (const float4*)&xt[8 * tid];
        #pragma unroll
        for (int i = 0; i < 4; ++i) {
            float4 a = xr[i];
            xv[4*i] = a.x; xv[4*i+1] = a.y; xv[4*i+2] = a.z; xv[4*i+3] = a.w;
        }
        float2 a4 = *(const float2*)&xt[8 * tid + 16];
        xv[16] = a4.x; xv[17] = a4.y;

        float s8 = 0.0f;
        #pragma unroll
        for (int p = 0; p < 8; ++p) s8 += xv[p];
        X += s8;
        #pragma unroll
        for (int l = 0; l < 11; ++l) {
            float r = 0.0f;
            #pragma unroll
            for (int p = 0; p < 8; ++p) r = fmaf(xv[p], xv[p + l], r);
            R[l] += r;
        }

        if (blockIdx.x < 32) {
            // row 0: this tile covers pooled bins 8*block + 2*it + {0,1}
            float ps = s8;
            #pragma unroll
            for (int off = 32; off; off >>= 1) ps += __shfl_down(ps, off);
            if ((tid & 63) == 0) wsum[tid >> 6] = ps;
            __syncthreads();
            if (tid == 0) {
                pooled[blockIdx.x * 8 + 2 * it]     = (wsum[0] + wsum[1]) * (1.0f / 1024.0f);
                pooled[blockIdx.x * 8 + 2 * it + 1] = (wsum[2] + wsum[3]) * (1.0f / 1024.0f);
            }
        }
        __syncthreads();
    }

    // block-reduce 12 values -> part
    #pragma unroll
    for (int off = 32; off; off >>= 1) {
        X += __shfl_down(X, off);
        #pragma unroll
        for (int l = 0; l < 11; ++l) R[l] += __shfl_down(R[l], off);
    }
    __shared__ float red[4][12];
    int wave = tid >> 6;
    if ((tid & 63) == 0) {
        red[wave][0] = X;
        #pragma unroll
        for (int l = 0; l < 11; ++l) red[wave][1 + l] = R[l];
    }
    __syncthreads();
    if (tid < 12)
        part[tid * 1024 + blockIdx.x] = red[0][tid] + red[1][tid] + red[2][tid] + red[3][tid];
}

// ============ K2: attention MLP + softmax + partial reduce + BN fold ============
// 1 block x 256 threads.
__global__ void attn_finalize_kernel(const float* __restrict__ w1, const float* __restrict__ b1,
                                     const float* __restrict__ w2, const float* __restrict__ b2,
                                     KPtrs kp, const float* __restrict__ pooled,
                                     const float* __restrict__ part,
                                     const float* __restrict__ gamma, const float* __restrict__ beta,
                                     float* __restrict__ Kscl, float* __restrict__ biasv) {
    __shared__ float h[128];
    __shared__ float logits[12];
    __shared__ float s[12];
    __shared__ float Kr[220];
    __shared__ double vals[12];
    __shared__ float g[4];
    int tid = threadIdx.x;
    int w = tid >> 6, lane = tid & 63;

    float4 pv = ((const float4*)pooled)[lane];
    // layer 1: wave w rows 32w .. 32w+31
    for (int i = 0; i < 32; ++i) {
        int t = w * 32 + i;
        float4 wv = ((const float4*)(w1 + t * 256))[lane];
        float p = wv.x * pv.x + wv.y * pv.y + wv.z * pv.z + wv.w * pv.w;
        #pragma unroll
        for (int off = 32; off; off >>= 1) p += __shfl_down(p, off);
        if (lane == 0) h[t] = fmaxf(p + b1[t], 0.0f);
    }
    __syncthreads();
    // layer 2: wave w rows f = w, w+4, w+8
    for (int f = w; f < 12; f += 4) {
        float2 wv = ((const float2*)(w2 + f * 128))[lane];
        float p = wv.x * h[2 * lane] + wv.y * h[2 * lane + 1];
        #pragma unroll
        for (int off = 32; off; off >>= 1) p += __shfl_down(p, off);
        if (lane == 0) logits[f] = p + b2[f];
    }
    __syncthreads();
    if (tid == 0) {
        float m = logits[0];
        #pragma unroll
        for (int i = 1; i < 12; ++i) m = fmaxf(m, logits[i]);
        float e[12]; float sum = 0.0f;
        #pragma unroll
        for (int i = 0; i < 12; ++i) { e[i] = expf(logits[i] - m); sum += e[i]; }
        float inv = 1.0f / sum;
        #pragma unroll
        for (int i = 0; i < 12; ++i) s[i] = e[i] * inv;
    }
    __syncthreads();
    constexpr int KSa[12] = {3,3,3,5,5,7,7,7,9,9,11,11};
    if (tid < 220) {
        int q = tid / 44, r = tid % 44, c = r / 11, j = r % 11;
        int kmax = 2 * q + 3;
        float v = 0.0f;
        #pragma unroll
        for (int i = 0; i < 12; ++i) {
            int k = KSa[i];
            if (k <= kmax && j < k) v = fmaf(s[i], kp.p[i][c * k + j], v);
        }
        Kr[tid] = v;
    }
    // reduce partials: wave w handles v = w, w+4, w+8 over 1024 blocks
    for (int v = w; v < 12; v += 4) {
        double d = 0.0;
        #pragma unroll 4
        for (int i = 0; i < 16; ++i) d += (double)part[v * 1024 + i * 64 + lane];
        #pragma unroll
        for (int off = 32; off; off >>= 1) d += __shfl_down(d, off);
        if (lane == 0) vals[v] = d;
    }
    __syncthreads();
    if (tid < 4) {
        int c = tid;
        const float* Kc = Kr + 4 * 44 + c * 11;   // full-kernel class
        double sK = 0.0;
        for (int j = 0; j < 11; ++j) sK += (double)Kc[j];
        double mean = sK * vals[0] / NTOT;
        double ex2 = 0.0;
        for (int l = 0; l < 11; ++l) {
            double A = 0.0;
            for (int j = 0; j + l < 11; ++j) A += (double)Kc[j] * (double)Kc[j + l];
            ex2 += (l ? 2.0 : 1.0) * A * vals[1 + l];
        }
        ex2 /= NTOT;
        double var = ex2 - mean * mean;
        float gg = gamma[c] * (float)(1.0 / sqrt(var + 1e-5));
        g[c] = gg;
        biasv[c] = beta[c] - (float)mean * gg;
    }
    __syncthreads();
    if (tid < 220) {
        int c = (tid / 11) % 4;
        Kscl[tid] = Kr[tid] * g[c];
    }
}

// ============ K3: write pass — 2048-tile, 8 outputs/thread/channel, all-dwordx4 stores ============
// grid 4096 = 32 rows x 128 segs. Odd channels shifted +2 (row base ≡ 2 mod 4) so every
// fast-path store is 16B-aligned dwordx4. Head (t=0,1 odd c) and tail handled scalar.
__global__ __launch_bounds__(256, 4) void write_kernel(const float* __restrict__ x,
                                                       const float* __restrict__ Kscl,
                                                       const float* __restrict__ biasv,
                                                       float* __restrict__ out) {
    __shared__ float xt[2064];
    int tid = threadIdx.x;
    int b = blockIdx.x >> 7, seg = blockIdx.x & 127;
    int base = seg << 11;
    const float* xb = x + b * L_LEN;

    *(float4*)&xt[4 * tid]        = *(const float4*)(xb + base + 4 * tid);
    *(float4*)&xt[1024 + 4 * tid] = *(const float4*)(xb + base + 1024 + 4 * tid);
    if (tid < 3) {
        float4 v = {0.f, 0.f, 0.f, 0.f};
        if (seg < 127) v = *(const float4*)(xb + base + 2048 + 4 * tid);
        *(float4*)&xt[2048 + 4 * tid] = v;
    }

    float K[4][11], bias[4];
    #pragma unroll
    for (int c = 0; c < 4; ++c) {
        #pragma unroll
        for (int j = 0; j < 11; ++j) K[c][j] = Kscl[4 * 44 + c * 11 + j];
        bias[c] = biasv[c];
    }
    __syncthreads();

    bool tail = (seg == 127) && (tid >= 254);
    if (!tail) {
        float xv[20];
        const float4* xr = (const float4*)&xt[8 * tid];
        #pragma unroll
        for (int i = 0; i < 5; ++i) {
            float4 a = xr[i];
            xv[4*i] = a.x; xv[4*i+1] = a.y; xv[4*i+2] = a.z; xv[4*i+3] = a.w;
        }
        #pragma unroll
        for (int c = 0; c < 4; ++c) {
            int sh = (c & 1) ? 2 : 0;
            float v[8];
            #pragma unroll
            for (int p = 0; p < 8; ++p) {
                float a = bias[c];
                #pragma unroll
                for (int j = 0; j < 11; ++j) a = fmaf(K[c][j], xv[sh + p + j], a);
                v[p] = fmaxf(a, 0.0f);
            }
            float* op = out + (size_t)(4 * b + c) * OUT_LEN + base + sh + 8 * tid;
            *(v4f*)op       = (v4f){v[0], v[1], v[2], v[3]};
            *(v4f*)(op + 4) = (v4f){v[4], v[5], v[6], v[7]};
        }
    } else {
        // seg==127, tid in {254,255}: per-position cumulative-class scalar path
        #pragma unroll
        for (int par = 0; par < 2; ++par) {           // par 0: even c base, 1: odd (+2)
            int t0 = base + 2 * par + 8 * tid;
            for (int tt = 0; tt < 8; ++tt) {
                int t = t0 + tt;
                if (t >= OUT_LEN) break;
                int rem = L_LEN - t;
                int q = (rem - 3) >> 1; if (q > 4) q = 4;
                int kmax = 2 * q + 3;
                int lt = t - base;
                for (int c = par; c < 4; c += 2) {
                    float a = bias[c];
                    for (int j = 0; j < kmax; ++j) a = fmaf(Kscl[q * 44 + c * 11 + j], xt[lt + j], a);
                    out[(size_t)(4 * b + c) * OUT_LEN + t] = fmaxf(a, 0.0f);
                }
            }
        }
    }
    // head: odd channels' outputs t=0,1 (not covered by shifted quads)
    if (seg == 0 && tid == 0) {
        for (int c = 1; c < 4; c += 2) {
            for (int t = 0; t < 2; ++t) {
                float a = bias[c];
                #pragma unroll
                for (int j = 0; j < 11; ++j) a = fmaf(K[c][j], xt[t + j], a);
                out[(size_t)(4 * b + c) * OUT_LEN + t] = fmaxf(a, 0.0f);
            }
        }
    }
}

extern "C" void kernel_launch(void* const* d_in, const int* in_sizes, int n_in,
                              void* d_out, int out_size, void* d_ws, size_t ws_size,
                              hipStream_t stream) {
    const float* x     = (const float*)d_in[0];
    const float* w1    = (const float*)d_in[1];
    const float* b1    = (const float*)d_in[2];
    const float* w2    = (const float*)d_in[3];
    const float* b2    = (const float*)d_in[4];
    const float* gamma = (const float*)d_in[5];
    const float* beta  = (const float*)d_in[6];
    KPtrs kp;
    for (int i = 0; i < 12; ++i) kp.p[i] = (const float*)d_in[7 + i];
    float* out = (float*)d_out;

    char* ws = (char*)d_ws;
    float* pooled = (float*)(ws + 0);       // 256 floats
    float* Kscl   = (float*)(ws + 1024);    // 220 floats
    float* biasv  = (float*)(ws + 2048);    // 4 floats
    float* part   = (float*)(ws + 4096);    // 12*1024 floats = 48 KB

    stats_pool_kernel<<<dim3(1024), dim3(256), 0, stream>>>(x, part, pooled);
    attn_finalize_kernel<<<dim3(1), dim3(256), 0, stream>>>(w1, b1, w2, b2, kp, pooled,
                                                            part, gamma, beta, Kscl, biasv);
    write_kernel<<<dim3(4096), dim3(256), 0, stream>>>(x, Kscl, biasv, out);
}

// Round 7
// 65.208 us; speedup vs baseline: 4.4798x; 1.3984x over previous
//
#include <hip/hip_runtime.h>

#define L_LEN   262144
#define OUT_LEN 262142
#define BATCH   32
#define NTOT    (32.0 * 262142.0)

typedef float v4f __attribute__((ext_vector_type(4)));

struct KPtrs { const float* p[12]; };

// ============ K1: fused pool + autocorrelation stats ============
// grid 1024 x 256. Block handles 4 consecutive 2048-tiles (128 tiles/row, 4096 total).
// Accumulates X = sum(x), R_l = sum(x_u*x_{u+l}) l=0..10 per block (row-local; staging
// zero-pads past row end). Blocks 0..31 also emit pooled bins (row 0).
// part layout SoA: part[v*1024 + block], v=0 -> X, v=1+l -> R_l.
__global__ __launch_bounds__(256, 4) void stats_pool_kernel(const float* __restrict__ x,
                                                            float* __restrict__ part,
                                                            float* __restrict__ pooled) {
    __shared__ float xt[2064];
    __shared__ float wsum[4];
    int tid = threadIdx.x;
    float X = 0.0f, R[11];
    #pragma unroll
    for (int l = 0; l < 11; ++l) R[l] = 0.0f;

    for (int it = 0; it < 4; ++it) {
        int T = blockIdx.x * 4 + it;       // 0..4095
        int row = T >> 7, seg = T & 127;   // row 0..31, seg 0..127
        int base = seg << 11;
        const float* xb = x + row * L_LEN;
        *(float4*)&xt[4 * tid]        = *(const float4*)(xb + base + 4 * tid);
        *(float4*)&xt[1024 + 4 * tid] = *(const float4*)(xb + base + 1024 + 4 * tid);
        if (tid < 3) {
            float4 v = {0.f, 0.f, 0.f, 0.f};
            if (seg < 127) v = *(const float4*)(xb + base + 2048 + 4 * tid);
            *(float4*)&xt[2048 + 4 * tid] = v;
        }
        __syncthreads();

        float xv[18];
        const float4* xr = (const float4*)&xt[8 * tid];
        #pragma unroll
        for (int i = 0; i < 4; ++i) {
            float4 a = xr[i];
            xv[4*i] = a.x; xv[4*i+1] = a.y; xv[4*i+2] = a.z; xv[4*i+3] = a.w;
        }
        float2 a4 = *(const float2*)&xt[8 * tid + 16];
        xv[16] = a4.x; xv[17] = a4.y;

        float s8 = 0.0f;
        #pragma unroll
        for (int p = 0; p < 8; ++p) s8 += xv[p];
        X += s8;
        #pragma unroll
        for (int l = 0; l < 11; ++l) {
            float r = 0.0f;
            #pragma unroll
            for (int p = 0; p < 8; ++p) r = fmaf(xv[p], xv[p + l], r);
            R[l] += r;
        }

        if (blockIdx.x < 32) {
            // row 0: this tile covers pooled bins 8*block + 2*it + {0,1}
            float ps = s8;
            #pragma unroll
            for (int off = 32; off; off >>= 1) ps += __shfl_down(ps, off);
            if ((tid & 63) == 0) wsum[tid >> 6] = ps;
            __syncthreads();
            if (tid == 0) {
                pooled[blockIdx.x * 8 + 2 * it]     = (wsum[0] + wsum[1]) * (1.0f / 1024.0f);
                pooled[blockIdx.x * 8 + 2 * it + 1] = (wsum[2] + wsum[3]) * (1.0f / 1024.0f);
            }
        }
        __syncthreads();
    }

    // block-reduce 12 values -> part
    #pragma unroll
    for (int off = 32; off; off >>= 1) {
        X += __shfl_down(X, off);
        #pragma unroll
        for (int l = 0; l < 11; ++l) R[l] += __shfl_down(R[l], off);
    }
    __shared__ float red[4][12];
    int wave = tid >> 6;
    if ((tid & 63) == 0) {
        red[wave][0] = X;
        #pragma unroll
        for (int l = 0; l < 11; ++l) red[wave][1 + l] = R[l];
    }
    __syncthreads();
    if (tid < 12)
        part[tid * 1024 + blockIdx.x] = red[0][tid] + red[1][tid] + red[2][tid] + red[3][tid];
}

// ============ K2: attention MLP + softmax + partial reduce + BN fold ============
// 1 block x 1024 threads (16 waves -> layer-1 serial depth 8).
__global__ void attn_finalize_kernel(const float* __restrict__ w1, const float* __restrict__ b1,
                                     const float* __restrict__ w2, const float* __restrict__ b2,
                                     KPtrs kp, const float* __restrict__ pooled,
                                     const float* __restrict__ part,
                                     const float* __restrict__ gamma, const float* __restrict__ beta,
                                     float* __restrict__ Kscl, float* __restrict__ biasv) {
    __shared__ float h[128];
    __shared__ float logits[12];
    __shared__ float s[12];
    __shared__ float Kr[220];
    __shared__ double vals[12];
    __shared__ float g[4];
    int tid = threadIdx.x;
    int w = tid >> 6, lane = tid & 63;

    float4 pv = ((const float4*)pooled)[lane];
    // layer 1: wave w rows 8w .. 8w+7
    for (int i = 0; i < 8; ++i) {
        int t = w * 8 + i;
        float4 wv = ((const float4*)(w1 + t * 256))[lane];
        float p = wv.x * pv.x + wv.y * pv.y + wv.z * pv.z + wv.w * pv.w;
        #pragma unroll
        for (int off = 32; off; off >>= 1) p += __shfl_down(p, off);
        if (lane == 0) h[t] = fmaxf(p + b1[t], 0.0f);
    }
    __syncthreads();
    // layer 2: waves 0..11, one row each
    if (w < 12) {
        float2 wv = ((const float2*)(w2 + w * 128))[lane];
        float p = wv.x * h[2 * lane] + wv.y * h[2 * lane + 1];
        #pragma unroll
        for (int off = 32; off; off >>= 1) p += __shfl_down(p, off);
        if (lane == 0) logits[w] = p + b2[w];
    }
    __syncthreads();
    if (tid == 0) {
        float m = logits[0];
        #pragma unroll
        for (int i = 1; i < 12; ++i) m = fmaxf(m, logits[i]);
        float e[12]; float sum = 0.0f;
        #pragma unroll
        for (int i = 0; i < 12; ++i) { e[i] = expf(logits[i] - m); sum += e[i]; }
        float inv = 1.0f / sum;
        #pragma unroll
        for (int i = 0; i < 12; ++i) s[i] = e[i] * inv;
    }
    __syncthreads();
    constexpr int KSa[12] = {3,3,3,5,5,7,7,7,9,9,11,11};
    if (tid < 220) {
        int q = tid / 44, r = tid % 44, c = r / 11, j = r % 11;
        int kmax = 2 * q + 3;
        float v = 0.0f;
        #pragma unroll
        for (int i = 0; i < 12; ++i) {
            int k = KSa[i];
            if (k <= kmax && j < k) v = fmaf(s[i], kp.p[i][c * k + j], v);
        }
        Kr[tid] = v;
    }
    // reduce partials: wave w (w<12) handles value w over 1024 blocks
    if (w < 12) {
        double d = 0.0;
        #pragma unroll 4
        for (int i = 0; i < 16; ++i) d += (double)part[w * 1024 + i * 64 + lane];
        #pragma unroll
        for (int off = 32; off; off >>= 1) d += __shfl_down(d, off);
        if (lane == 0) vals[w] = d;
    }
    __syncthreads();
    if (tid < 4) {
        int c = tid;
        const float* Kc = Kr + 4 * 44 + c * 11;   // full-kernel class
        double sK = 0.0;
        for (int j = 0; j < 11; ++j) sK += (double)Kc[j];
        double mean = sK * vals[0] / NTOT;
        double ex2 = 0.0;
        for (int l = 0; l < 11; ++l) {
            double A = 0.0;
            for (int j = 0; j + l < 11; ++j) A += (double)Kc[j] * (double)Kc[j + l];
            ex2 += (l ? 2.0 : 1.0) * A * vals[1 + l];
        }
        ex2 /= NTOT;
        double var = ex2 - mean * mean;
        float gg = gamma[c] * (float)(1.0 / sqrt(var + 1e-5));
        g[c] = gg;
        biasv[c] = beta[c] - (float)mean * gg;
    }
    __syncthreads();
    if (tid < 220) {
        int c = (tid / 11) % 4;
        Kscl[tid] = Kr[tid] * g[c];
    }
}

// ============ K3: write pass — 2048-tile, lane-contiguous dwordx4 stores ============
// grid 4096 = 32 rows x 128 segs. Thread = 4 consecutive outputs x 2 half-tiles x 4 ch.
// Odd channels shifted +2 (row base ≡ 2 mod 4) so every store is 16B-aligned dwordx4
// with 16B lane stride (wave writes 1KB contiguous). Head/tail scalar fixups.
__global__ __launch_bounds__(256, 4) void write_kernel(const float* __restrict__ x,
                                                       const float* __restrict__ Kscl,
                                                       const float* __restrict__ biasv,
                                                       float* __restrict__ out) {
    __shared__ float xt[2064];
    int tid = threadIdx.x;
    int b = blockIdx.x >> 7, seg = blockIdx.x & 127;
    int base = seg << 11;
    const float* xb = x + b * L_LEN;

    *(float4*)&xt[4 * tid]        = *(const float4*)(xb + base + 4 * tid);
    *(float4*)&xt[1024 + 4 * tid] = *(const float4*)(xb + base + 1024 + 4 * tid);
    if (tid < 4) {
        float4 v = {0.f, 0.f, 0.f, 0.f};
        if (seg < 127) v = *(const float4*)(xb + base + 2048 + 4 * tid);
        *(float4*)&xt[2048 + 4 * tid] = v;
    }

    float K[4][11], bias[4];
    #pragma unroll
    for (int c = 0; c < 4; ++c) {
        #pragma unroll
        for (int j = 0; j < 11; ++j) K[c][j] = Kscl[4 * 44 + c * 11 + j];
        bias[c] = biasv[c];
    }
    __syncthreads();

    #pragma unroll
    for (int gdx = 0; gdx < 2; ++gdx) {
        int lt = gdx * 1024 + 4 * tid;
        bool scalar = (seg == 127) && (gdx == 1) && (tid >= 253);
        if (!scalar) {
            float xv[16];
            const float4* xr = (const float4*)&xt[lt];
            #pragma unroll
            for (int i = 0; i < 4; ++i) {
                float4 a = xr[i];
                xv[4*i] = a.x; xv[4*i+1] = a.y; xv[4*i+2] = a.z; xv[4*i+3] = a.w;
            }
            #pragma unroll
            for (int c = 0; c < 4; ++c) {
                int sh = (c & 1) ? 2 : 0;
                float v[4];
                #pragma unroll
                for (int p = 0; p < 4; ++p) {
                    float a = bias[c];
                    #pragma unroll
                    for (int j = 0; j < 11; ++j) a = fmaf(K[c][j], xv[sh + p + j], a);
                    v[p] = fmaxf(a, 0.0f);
                }
                // addr ≡ 0 mod 4 floats: row base %4 = {0,2}, sh = {0,2} cancels
                float* op = out + (size_t)(4 * b + c) * OUT_LEN + base + sh + lt;
                *(v4f*)op = (v4f){v[0], v[1], v[2], v[3]};
            }
        } else {
            // seg==127, half-tile B, tid>=253: per-position cumulative-class + bounds
            #pragma unroll
            for (int par = 0; par < 2; ++par) {
                int sh = 2 * par;
                for (int p = 0; p < 4; ++p) {
                    int t = base + sh + lt + p;
                    if (t >= OUT_LEN) continue;
                    int rem = L_LEN - t;
                    int q = (rem - 3) >> 1; if (q > 4) q = 4;
                    int kmax = 2 * q + 3;
                    int li = sh + lt + p;
                    for (int c = par; c < 4; c += 2) {
                        float a = bias[c];
                        for (int j = 0; j < kmax; ++j) a = fmaf(Kscl[q * 44 + c * 11 + j], xt[li + j], a);
                        out[(size_t)(4 * b + c) * OUT_LEN + t] = fmaxf(a, 0.0f);
                    }
                }
            }
        }
    }
    // head: odd channels' outputs t=0,1 (not covered by shifted quads)
    if (seg == 0 && tid == 0) {
        for (int c = 1; c < 4; c += 2) {
            for (int t = 0; t < 2; ++t) {
                float a = bias[c];
                #pragma unroll
                for (int j = 0; j < 11; ++j) a = fmaf(K[c][j], xt[t + j], a);
                out[(size_t)(4 * b + c) * OUT_LEN + t] = fmaxf(a, 0.0f);
            }
        }
    }
}

extern "C" void kernel_launch(void* const* d_in, const int* in_sizes, int n_in,
                              void* d_out, int out_size, void* d_ws, size_t ws_size,
                              hipStream_t stream) {
    const float* x     = (const float*)d_in[0];
    const float* w1    = (const float*)d_in[1];
    const float* b1    = (const float*)d_in[2];
    const float* w2    = (const float*)d_in[3];
    const float* b2    = (const float*)d_in[4];
    const float* gamma = (const float*)d_in[5];
    const float* beta  = (const float*)d_in[6];
    KPtrs kp;
    for (int i = 0; i < 12; ++i) kp.p[i] = (const float*)d_in[7 + i];
    float* out = (float*)d_out;

    char* ws = (char*)d_ws;
    float* pooled = (float*)(ws + 0);       // 256 floats
    float* Kscl   = (float*)(ws + 1024);    // 220 floats
    float* biasv  = (float*)(ws + 2048);    // 4 floats
    float* part   = (float*)(ws + 4096);    // 12*1024 floats = 48 KB

    stats_pool_kernel<<<dim3(1024), dim3(256), 0, stream>>>(x, part, pooled);
    attn_finalize_kernel<<<dim3(1), dim3(1024), 0, stream>>>(w1, b1, w2, b2, kp, pooled,
                                                             part, gamma, beta, Kscl, biasv);
    write_kernel<<<dim3(4096), dim3(256), 0, stream>>>(x, Kscl, biasv, out);
}